// Round 8
// baseline (356.712 us; speedup 1.0000x reference)
//
#include <hip/hip_runtime.h>

// GMLLM dual-stream self-attention, MI355X/gfx950.  Round 11:
//  attn: v10 schedule kept line-for-line, block reshaped 256->512 threads
//  (8 waves x 16 q-rows instead of 4 x 32). Same 128-row tile, same grid 768,
//  same 48KB LDS -> still 3 blocks/CU but 24 waves/CU (6/SIMD, was 3/SIMD).
//  Per-wave regs halve (aq[4], O[4], sacc[4], scalar lsum) -> fits 85-VGPR/6-wave
//  budget. Doubled wave-level overlap attacks the latency regime (all pipes <50%).
//   - S^T = mfma(K,Q), O^T = mfma(V^T,P^T); P trunc-pack b64 sS, b128 reads
//   - schedule: QK -> bar1 -> stage K(t+1)+V(t+1) -> softmax+PV -> bar2
//  proj/casts/pack identical to round 10 (passing).

typedef __attribute__((ext_vector_type(8))) short short8;   // 8 x bf16 (4 VGPRs) MFMA A/B frag
typedef __attribute__((ext_vector_type(4))) float floatx4;  // MFMA C/D frag

#define LOG2E 1.4426950408889634f
#define QSCL 0.18033688011112042f   /* 0.125 * log2(e) */

static constexpr int Sn = 2048, Dn = 768, Hn = 12, BHn = 48;

__device__ __forceinline__ unsigned short f2bf(float f) {
  unsigned u = __float_as_uint(f);
  u += 0x7FFFu + ((u >> 16) & 1u);          // RNE
  return (unsigned short)(u >> 16);
}

typedef const __attribute__((address_space(1))) unsigned int* gas_t;
typedef __attribute__((address_space(3))) unsigned int* las_t;
__device__ __forceinline__ void async16(const void* g, void* l) {
  // async 16B/lane global->LDS; LDS dest = wave-uniform base + lane*16
  __builtin_amdgcn_global_load_lds((gas_t)g, (las_t)l, 16, 0, 0);
}

// ---------------- cast hidden_states f32 -> bf16 (row-major [8192][768]) ----------------
__global__ void cast_hs_kernel(const float* __restrict__ in, unsigned short* __restrict__ out, int n4) {
  int i = blockIdx.x * 256 + threadIdx.x;
  if (i >= n4) return;
  float4 v = ((const float4*)in)[i];
  ushort4 o = make_ushort4(f2bf(v.x), f2bf(v.y), f2bf(v.z), f2bf(v.w));
  ((ushort4*)out)[i] = o;
}

// ---------------- cast Wq/Wk/Wv f32 -> bf16, stacked [3][768][768] ----------------
__global__ void cast_w_kernel(const float* __restrict__ w0, const float* __restrict__ w1,
                              const float* __restrict__ w2, unsigned short* __restrict__ out) {
  int i = blockIdx.x * 256 + threadIdx.x;
  const float* src = (blockIdx.y == 0) ? w0 : (blockIdx.y == 1) ? w1 : w2;
  float4 v = ((const float4*)src)[i];
  ushort4 o = make_ushort4(f2bf(v.x), f2bf(v.y), f2bf(v.z), f2bf(v.w));
  ((ushort4*)(out + (size_t)blockIdx.y * Dn * Dn))[i] = o;
}

// ---------------- pack layout_q (pre-scaled) / layout_k into upper half of Qc/Kc ----------------
__global__ void pack_layout_kernel(const float* __restrict__ lq, const float* __restrict__ lk,
                                   unsigned short* __restrict__ Qc, unsigned short* __restrict__ Kc) {
  int idx = blockIdx.x * 256 + threadIdx.x;           // 786432 threads
  const float* src = blockIdx.y ? lk : lq;
  unsigned short* dst = blockIdx.y ? Kc : Qc;
  const float sc = blockIdx.y ? 1.0f : QSCL;
  int d8 = idx & 7;
  int tt = idx >> 3;
  int h = tt % Hn;
  int bs = tt / Hn;
  int b = bs >> 11, s = bs & (Sn - 1);
  float4 v0 = ((const float4*)src)[idx * 2];
  float4 v1 = ((const float4*)src)[idx * 2 + 1];
  short8 o;
  o[0] = (short)f2bf(v0.x * sc); o[1] = (short)f2bf(v0.y * sc);
  o[2] = (short)f2bf(v0.z * sc); o[3] = (short)f2bf(v0.w * sc);
  o[4] = (short)f2bf(v1.x * sc); o[5] = (short)f2bf(v1.y * sc);
  o[6] = (short)f2bf(v1.z * sc); o[7] = (short)f2bf(v1.w * sc);
  size_t off = ((size_t)(b * Hn + h) * Sn + s) * 128 + 64 + d8 * 8;
  *(short8*)(dst + off) = o;
}

// ---------------- QKV projection (round-9 version, passing) ----------------
__global__ __launch_bounds__(256, 3)
void proj_kernel(const unsigned short* __restrict__ X,   // [8192][768] bf16
                 const unsigned short* __restrict__ Wb,  // [3][768][768] bf16
                 const float* __restrict__ bq, const float* __restrict__ bk, const float* __restrict__ bv,
                 unsigned short* __restrict__ Qc, unsigned short* __restrict__ Kc,
                 unsigned short* __restrict__ Vt) {
  __shared__ __align__(16) unsigned short sMem[16384];

  const int z = blockIdx.z;
  const unsigned short* W = Wb + (size_t)z * Dn * Dn;
  const float* bias = (z == 0) ? bq : (z == 1) ? bk : bv;

  const int t = threadIdx.x;
  const int lane = t & 63, wave = t >> 6;
  const int wm = wave >> 1, wn = wave & 1;
  const int quad = lane >> 4, col15 = lane & 15;
  const int m0 = blockIdx.y * 128, n0 = blockIdx.x * 128;

  const int srow = lane >> 2, schunk = lane & 3;   // staging: 16 rows/call, 4 chunks/row

  floatx4 acc[4][4];
#pragma unroll
  for (int i = 0; i < 4; i++)
#pragma unroll
    for (int j = 0; j < 4; j++) acc[i][j] = (floatx4){0.f, 0.f, 0.f, 0.f};

  auto stageAB = [&](int kt, int buf) {
    unsigned short* sA = sMem + buf * 4096;
    unsigned short* sB = sMem + 8192 + buf * 4096;
#pragma unroll
    for (int c = 0; c < 2; c++) {
      int row = wave * 32 + c * 16 + srow;
      async16(X + (size_t)(m0 + row) * Dn + kt * 32 + schunk * 8, sA + (wave * 32 + c * 16) * 32);
      async16(W + (size_t)(n0 + row) * Dn + kt * 32 + schunk * 8, sB + (wave * 32 + c * 16) * 32);
    }
  };

  stageAB(0, 0);
  __syncthreads();

  for (int kt = 0; kt < 24; kt++) {
    const int cur = kt & 1;
    if (kt + 1 < 24) stageAB(kt + 1, cur ^ 1);
    const unsigned short* sA = sMem + cur * 4096;
    const unsigned short* sB = sMem + 8192 + cur * 4096;
    short8 af[4], bf[4];
#pragma unroll
    for (int i = 0; i < 4; i++)
      af[i] = *(const short8*)(sA + (wm * 64 + i * 16 + col15) * 32 + quad * 8);
#pragma unroll
    for (int j = 0; j < 4; j++)
      bf[j] = *(const short8*)(sB + (wn * 64 + j * 16 + col15) * 32 + quad * 8);
#pragma unroll
    for (int i = 0; i < 4; i++)
#pragma unroll
      for (int j = 0; j < 4; j++)
        acc[i][j] = __builtin_amdgcn_mfma_f32_16x16x32_bf16(af[i], bf[j], acc[i][j], 0, 0, 0);
    __syncthreads();
  }

  const int b = m0 >> 11;
  const int s0g = m0 & (Sn - 1);
  const int h0 = n0 >> 6;

  if (z < 2) {
    const float scl = (z == 0) ? QSCL : 1.0f;
    unsigned short* dst0 = (z == 0) ? Qc : Kc;
#pragma unroll
    for (int j = 0; j < 4; j++) {
      int nl = wn * 64 + j * 16 + col15;
      float bias_n = bias[n0 + nl];
#pragma unroll
      for (int i = 0; i < 4; i++) {
        int mb = wm * 64 + i * 16 + quad * 4;
#pragma unroll
        for (int r = 0; r < 4; r++) {
          int m = mb + r;
          sMem[m * 128 + (nl ^ (((m >> 2) & 3) << 4))] = f2bf((acc[i][j][r] + bias_n) * scl);
        }
      }
    }
    __syncthreads();
#pragma unroll
    for (int cc = 0; cc < 8; cc++) {
      int idx = cc * 256 + t;
      int m = idx >> 4, piece = idx & 15;
      int h = h0 + (piece >> 3), d8 = piece & 7;
      short8 v = *(const short8*)(sMem + m * 128 + (piece ^ (((m >> 2) & 3) << 1)) * 8);
      *(short8*)(dst0 + ((size_t)(b * Hn + h) * Sn + s0g + m) * 128 + d8 * 8) = v;
    }
  } else {
#pragma unroll
    for (int j = 0; j < 4; j++) {
      int nl = wn * 64 + j * 16 + col15;
      float bias_n = bias[n0 + nl];
#pragma unroll
      for (int i = 0; i < 4; i++) {
        int mb = wm * 64 + i * 16 + quad * 4;
        ushort4 pk = make_ushort4(f2bf(acc[i][j][0] + bias_n), f2bf(acc[i][j][1] + bias_n),
                                  f2bf(acc[i][j][2] + bias_n), f2bf(acc[i][j][3] + bias_n));
        *(ushort4*)(sMem + nl * 128 + (mb ^ ((nl & 7) << 4))) = pk;
      }
    }
    __syncthreads();
#pragma unroll
    for (int cc = 0; cc < 8; cc++) {
      int idx = cc * 256 + t;
      int nl = idx >> 4, piece = idx & 15;
      int h = h0 + (nl >> 6), d = nl & 63;
      short8 v = *(const short8*)(sMem + nl * 128 + (piece ^ ((nl & 7) << 1)) * 8);
      *(short8*)(Vt + ((size_t)(b * Hn + h) * 64 + d) * Sn + s0g + piece * 8) = v;
    }
  }
}

// ---------------- flash attention v4: v10 schedule, 8 waves x 16 q-rows ----------------
// S^T = mfma(K,Q): lane (quad,col15) reg r holds S[q = blk+col15][k = jm*16+quad*4+r].
// P trunc-packed -> 4x b64 sS writes/wave-tile (phys col = k ^ ((col15&7)<<3));
// PV reads b128 with same involution.  O^T = mfma(V^T, P^T).  lsum per-lane, quad-reduced.
// Schedule: QK(t) -> bar1 -> stage K(t+1)(single) + V(t+1)(dbuf) -> softmax+PV(t) -> bar2.
// LDS 48KB, 512 threads -> 3 blocks/CU x 8 waves = 24 waves/CU (6/SIMD).
__global__ __launch_bounds__(512, 6)
void attn_kernel(const unsigned short* __restrict__ Qc,  // [BH][S][128], pre-scaled by QSCL
                 const unsigned short* __restrict__ Kc,  // [BH][S][128]
                 const unsigned short* __restrict__ Vt,  // [BH][64][S]
                 const float* __restrict__ mask,         // [B][S]
                 float* __restrict__ out) {              // [B][S][768]
  __shared__ __align__(16) unsigned short sK[64 * 128];     // 16KB single buffer, swizzled
  __shared__ __align__(16) unsigned short sV2[2][64 * 64];  // 16KB dbuf, swizzled
  __shared__ __align__(16) unsigned short sS[128 * 64];     // 16KB P^T, wave-private rows

  const int t = threadIdx.x;
  const int lane = t & 63, wave = t >> 6;                // wave 0..7
  const int quad = lane >> 4, col15 = lane & 15;
  const int swz = (col15 & 7) << 3;                      // sS k swizzle (shorts): phys = k ^ swz

  // XCD-aware swizzle: all 16 q-blocks of one bh share id&7 (L2 K/V reuse)
  const int id = blockIdx.x;
  const int slot = id >> 3;
  const int bh = (id & 7) + 8 * (slot >> 4);
  const int q0 = (slot & 15) * 128;
  const int b = bh / Hn, h = bh % Hn;

  // Q fragments (B-operand: col=q=lane&15, k-rows quad*8); 16 q-rows per wave
  short8 aq[4];
  const unsigned short* Qbase = Qc + ((size_t)bh * Sn + q0) * 128;
#pragma unroll
  for (int kk = 0; kk < 4; kk++)
    aq[kk] = *(const short8*)(Qbase + (size_t)(wave * 16 + col15) * 128 + kk * 32 + quad * 8);

  floatx4 O[4];
  float lsum = 0.f;
#pragma unroll
  for (int j = 0; j < 4; j++) O[j] = (floatx4){0.f, 0.f, 0.f, 0.f};

  const unsigned short* Kbase = Kc + (size_t)bh * Sn * 128;
  const unsigned short* Vbase = Vt + (size_t)bh * 64 * Sn;
  const float* mbase = mask + (size_t)b * Sn;

  const int krow = lane >> 4, kslot = lane & 15;  // sK staging: 4 rows/call
  const int vrow = lane >> 3, vslot = lane & 7;   // sV staging: 8 rows/call

  auto stageK = [&](int tile) {
#pragma unroll
    for (int c = 0; c < 2; c++) {                 // K tile 64x256B: 8 waves x 2 calls x 4 rows
      int row = wave * 8 + c * 4 + krow;
      int g = (kslot & 8) | ((kslot ^ row) & 7);
      async16(Kbase + (size_t)(tile * 64 + row) * 128 + g * 8, sK + (wave * 8 + c * 4) * 128);
    }
  };
  auto stageV = [&](int tile, int buf) {
    unsigned short* sVn = &sV2[buf][0];
    {                                             // V^T tile 64x128B: 8 waves x 1 call x 8 rows
      int row = wave * 8 + vrow;
      int g = vslot ^ (row & 7);
      async16(Vbase + (size_t)row * Sn + tile * 64 + g * 8, sVn + (wave * 8) * 64);
    }
  };

  constexpr int NT = Sn / 64;                     // 32 tiles
  stageK(0);
  stageV(0, 0);
  float mcur = mbase[lane] * LOG2E;               // tile-0 mask dword
  __syncthreads();                                // drain prologue staging

  for (int kt = 0; kt < NT; kt++) {
    const int cur = kt & 1;
    const unsigned short* sVcur = &sV2[cur][0];

    // ---- S^T(log2-domain) = Kcat Qcat^T  (reads sK) ----
    floatx4 sacc[4];                              // [jm = k subtile]
#pragma unroll
    for (int jm = 0; jm < 4; jm++) sacc[jm] = (floatx4){0.f, 0.f, 0.f, 0.f};
    __builtin_amdgcn_s_setprio(1);
#pragma unroll
    for (int kk = 0; kk < 4; kk++) {
      const int slotK = (((kk * 4 + quad) & 8) | (((kk * 4 + quad) ^ col15) & 7)) * 8;
#pragma unroll
      for (int jm = 0; jm < 4; jm++) {
        short8 ak = *(const short8*)(sK + (jm * 16 + col15) * 128 + slotK);
        sacc[jm] = __builtin_amdgcn_mfma_f32_16x16x32_bf16(ak, aq[kk], sacc[jm], 0, 0, 0);
      }
    }
    __builtin_amdgcn_s_setprio(0);

    const int tn = (kt + 1 < NT) ? kt + 1 : NT - 1;
    float mnew = mbase[tn * 64 + lane] * LOG2E;   // prefetch next tile's mask
    const bool nomask = __all(mcur == 0.0f);

    __syncthreads();                              // barrier1: all waves done reading sK
    if (kt + 1 < NT) {
      stageK(kt + 1);                             // rewrite single K buffer
      stageV(kt + 1, cur ^ 1);                    // fill other V buffer
    }

    // mask slow path: per-element additive value via lane shuffle (exact)
    float mvv[4][4];
    if (!nomask) {
#pragma unroll
      for (int jm = 0; jm < 4; jm++)
#pragma unroll
        for (int r = 0; r < 4; r++) mvv[jm][r] = __shfl(mcur, jm * 16 + quad * 4 + r);
    }

    // ---- softmax: p = exp2(s (+ mask)); trunc-pack -> b64 sS writes; lsum adds ----
    {
      unsigned short* srow = sS + (wave * 16 + col15) * 64;
      float lacc = 0.f;
#pragma unroll
      for (int jm = 0; jm < 4; jm++) {
        float p0 = sacc[jm][0], p1 = sacc[jm][1];
        float p2 = sacc[jm][2], p3 = sacc[jm][3];
        if (!nomask) { p0 += mvv[jm][0]; p1 += mvv[jm][1]; p2 += mvv[jm][2]; p3 += mvv[jm][3]; }
        unsigned u0 = __float_as_uint(__builtin_amdgcn_exp2f(p0)) & 0xFFFF0000u;
        unsigned u1 = __float_as_uint(__builtin_amdgcn_exp2f(p1)) & 0xFFFF0000u;
        unsigned u2 = __float_as_uint(__builtin_amdgcn_exp2f(p2)) & 0xFFFF0000u;
        unsigned u3 = __float_as_uint(__builtin_amdgcn_exp2f(p3)) & 0xFFFF0000u;
        lacc += (__uint_as_float(u0) + __uint_as_float(u1)) +
                (__uint_as_float(u2) + __uint_as_float(u3));
        uint2 w;
        w.x = (u0 >> 16) | u1;
        w.y = (u2 >> 16) | u3;
        *(uint2*)(srow + ((jm * 16 + quad * 4) ^ swz)) = w;
      }
      lsum += lacc;
    }
    // no barrier: sS rows are wave-private; intra-wave LDS RAW is ordered

    // ---- O^T += V^T P^T  (reads sS + sVcur) ----
    __builtin_amdgcn_s_setprio(1);
#pragma unroll
    for (int kk = 0; kk < 2; kk++) {
      short8 pb = *(const short8*)(sS + (wave * 16 + col15) * 64 + ((kk * 32 + quad * 8) ^ swz));
      const int slotV = ((kk * 4 + quad) ^ (col15 & 7)) * 8;
#pragma unroll
      for (int jd = 0; jd < 4; jd++) {
        short8 av = *(const short8*)(sVcur + (jd * 16 + col15) * 64 + slotV);
        O[jd] = __builtin_amdgcn_mfma_f32_16x16x32_bf16(av, pb, O[jd], 0, 0, 0);
      }
    }
    __builtin_amdgcn_s_setprio(0);

    __syncthreads();  // barrier2: drains K(t+1)/V(t+1) staging (issued ~900cy ago);
                      // all waves' PV reads of sVcur done before t+2 overwrites it
    mcur = mnew;
  }

  // ---- epilogue: l[q] = quad-reduced lsum; O^T cols divided, float4 stores ----
  {
    float s_ = lsum;
    s_ += __shfl_xor(s_, 16);
    s_ += __shfl_xor(s_, 32);
    float inv = 1.0f / s_;
    int qrow = q0 + wave * 16 + col15;
    float* obase = out + ((size_t)b * Sn + qrow) * Dn + h * 64 + quad * 4;
#pragma unroll
    for (int jd = 0; jd < 4; jd++) {
      float4 o4 = make_float4(O[jd][0] * inv, O[jd][1] * inv,
                              O[jd][2] * inv, O[jd][3] * inv);
      *(float4*)(obase + jd * 16) = o4;
    }
  }
}

extern "C" void kernel_launch(void* const* d_in, const int* in_sizes, int n_in,
                              void* d_out, int out_size, void* d_ws, size_t ws_size,
                              hipStream_t stream) {
  const float* hs   = (const float*)d_in[0];
  const float* lq   = (const float*)d_in[1];
  const float* lk   = (const float*)d_in[2];
  const float* mask = (const float*)d_in[3];
  const float* Wq   = (const float*)d_in[4];
  const float* bq   = (const float*)d_in[5];
  const float* Wk   = (const float*)d_in[6];
  const float* bk   = (const float*)d_in[7];
  const float* Wv   = (const float*)d_in[8];
  const float* bv   = (const float*)d_in[9];
  float* out = (float*)d_out;

  char* ws = (char*)d_ws;
  unsigned short* Xbf = (unsigned short*)ws;                         // [8192][768]
  unsigned short* Wbf = (unsigned short*)(ws + 12582912);            // [3][768][768]
  unsigned short* Qc  = (unsigned short*)(ws + 12582912 + 3538944);  // [48][2048][128]
  unsigned short* Kc  = Qc + (size_t)BHn * Sn * 128;
  unsigned short* Vt  = Kc + (size_t)BHn * Sn * 128;                 // [48][64][2048]

  cast_hs_kernel<<<6144, 256, 0, stream>>>(hs, Xbf, 1572864);
  cast_w_kernel<<<dim3(576, 3), 256, 0, stream>>>(Wq, Wk, Wv, Wbf);
  pack_layout_kernel<<<dim3(3072, 2), 256, 0, stream>>>(lq, lk, Qc, Kc);
  proj_kernel<<<dim3(6, 64, 3), 256, 0, stream>>>(Xbf, Wbf, bq, bk, bv, Qc, Kc, Vt);
  attn_kernel<<<768, 512, 0, stream>>>(Qc, Kc, Vt, mask, out);
}

// Round 9
// 290.883 us; speedup vs baseline: 1.2263x; 1.2263x over previous
//
#include <hip/hip_runtime.h>

// GMLLM dual-stream self-attention, MI355X/gfx950.  Round 12:
//  attn: round-11 8-wave kernel with the launch_bounds FIXED. r11 proved this
//  toolchain treats __launch_bounds__ arg2 as CUDA-style MIN BLOCKS/CU (not
//  waves/EU): (512,6) -> 48 waves/CU target -> 40 VGPR -> spills -> 156GB fetch.
//  (512,3) -> 3 blocks/CU -> 85-VGPR budget -> no spills. Same 24 waves/CU
//  (6/SIMD, 2x round-10) attacking the latency regime (all pipes <50%).
//   - S^T = mfma(K,Q), O^T = mfma(V^T,P^T); P trunc-pack b64 sS, b128 reads
//   - schedule: QK -> bar1 -> stage K(t+1)+V(t+1) -> softmax+PV -> bar2
//   - LDS 48KB, grid 768 = 256 CU x 3, zero tail
//  proj/casts/pack identical to round 10 (passing).

typedef __attribute__((ext_vector_type(8))) short short8;   // 8 x bf16 (4 VGPRs) MFMA A/B frag
typedef __attribute__((ext_vector_type(4))) float floatx4;  // MFMA C/D frag

#define LOG2E 1.4426950408889634f
#define QSCL 0.18033688011112042f   /* 0.125 * log2(e) */

static constexpr int Sn = 2048, Dn = 768, Hn = 12, BHn = 48;

__device__ __forceinline__ unsigned short f2bf(float f) {
  unsigned u = __float_as_uint(f);
  u += 0x7FFFu + ((u >> 16) & 1u);          // RNE
  return (unsigned short)(u >> 16);
}

typedef const __attribute__((address_space(1))) unsigned int* gas_t;
typedef __attribute__((address_space(3))) unsigned int* las_t;
__device__ __forceinline__ void async16(const void* g, void* l) {
  // async 16B/lane global->LDS; LDS dest = wave-uniform base + lane*16
  __builtin_amdgcn_global_load_lds((gas_t)g, (las_t)l, 16, 0, 0);
}

// ---------------- cast hidden_states f32 -> bf16 (row-major [8192][768]) ----------------
__global__ void cast_hs_kernel(const float* __restrict__ in, unsigned short* __restrict__ out, int n4) {
  int i = blockIdx.x * 256 + threadIdx.x;
  if (i >= n4) return;
  float4 v = ((const float4*)in)[i];
  ushort4 o = make_ushort4(f2bf(v.x), f2bf(v.y), f2bf(v.z), f2bf(v.w));
  ((ushort4*)out)[i] = o;
}

// ---------------- cast Wq/Wk/Wv f32 -> bf16, stacked [3][768][768] ----------------
__global__ void cast_w_kernel(const float* __restrict__ w0, const float* __restrict__ w1,
                              const float* __restrict__ w2, unsigned short* __restrict__ out) {
  int i = blockIdx.x * 256 + threadIdx.x;
  const float* src = (blockIdx.y == 0) ? w0 : (blockIdx.y == 1) ? w1 : w2;
  float4 v = ((const float4*)src)[i];
  ushort4 o = make_ushort4(f2bf(v.x), f2bf(v.y), f2bf(v.z), f2bf(v.w));
  ((ushort4*)(out + (size_t)blockIdx.y * Dn * Dn))[i] = o;
}

// ---------------- pack layout_q (pre-scaled) / layout_k into upper half of Qc/Kc ----------------
__global__ void pack_layout_kernel(const float* __restrict__ lq, const float* __restrict__ lk,
                                   unsigned short* __restrict__ Qc, unsigned short* __restrict__ Kc) {
  int idx = blockIdx.x * 256 + threadIdx.x;           // 786432 threads
  const float* src = blockIdx.y ? lk : lq;
  unsigned short* dst = blockIdx.y ? Kc : Qc;
  const float sc = blockIdx.y ? 1.0f : QSCL;
  int d8 = idx & 7;
  int tt = idx >> 3;
  int h = tt % Hn;
  int bs = tt / Hn;
  int b = bs >> 11, s = bs & (Sn - 1);
  float4 v0 = ((const float4*)src)[idx * 2];
  float4 v1 = ((const float4*)src)[idx * 2 + 1];
  short8 o;
  o[0] = (short)f2bf(v0.x * sc); o[1] = (short)f2bf(v0.y * sc);
  o[2] = (short)f2bf(v0.z * sc); o[3] = (short)f2bf(v0.w * sc);
  o[4] = (short)f2bf(v1.x * sc); o[5] = (short)f2bf(v1.y * sc);
  o[6] = (short)f2bf(v1.z * sc); o[7] = (short)f2bf(v1.w * sc);
  size_t off = ((size_t)(b * Hn + h) * Sn + s) * 128 + 64 + d8 * 8;
  *(short8*)(dst + off) = o;
}

// ---------------- QKV projection (round-9 version, passing) ----------------
__global__ __launch_bounds__(256, 3)
void proj_kernel(const unsigned short* __restrict__ X,   // [8192][768] bf16
                 const unsigned short* __restrict__ Wb,  // [3][768][768] bf16
                 const float* __restrict__ bq, const float* __restrict__ bk, const float* __restrict__ bv,
                 unsigned short* __restrict__ Qc, unsigned short* __restrict__ Kc,
                 unsigned short* __restrict__ Vt) {
  __shared__ __align__(16) unsigned short sMem[16384];

  const int z = blockIdx.z;
  const unsigned short* W = Wb + (size_t)z * Dn * Dn;
  const float* bias = (z == 0) ? bq : (z == 1) ? bk : bv;

  const int t = threadIdx.x;
  const int lane = t & 63, wave = t >> 6;
  const int wm = wave >> 1, wn = wave & 1;
  const int quad = lane >> 4, col15 = lane & 15;
  const int m0 = blockIdx.y * 128, n0 = blockIdx.x * 128;

  const int srow = lane >> 2, schunk = lane & 3;   // staging: 16 rows/call, 4 chunks/row

  floatx4 acc[4][4];
#pragma unroll
  for (int i = 0; i < 4; i++)
#pragma unroll
    for (int j = 0; j < 4; j++) acc[i][j] = (floatx4){0.f, 0.f, 0.f, 0.f};

  auto stageAB = [&](int kt, int buf) {
    unsigned short* sA = sMem + buf * 4096;
    unsigned short* sB = sMem + 8192 + buf * 4096;
#pragma unroll
    for (int c = 0; c < 2; c++) {
      int row = wave * 32 + c * 16 + srow;
      async16(X + (size_t)(m0 + row) * Dn + kt * 32 + schunk * 8, sA + (wave * 32 + c * 16) * 32);
      async16(W + (size_t)(n0 + row) * Dn + kt * 32 + schunk * 8, sB + (wave * 32 + c * 16) * 32);
    }
  };

  stageAB(0, 0);
  __syncthreads();

  for (int kt = 0; kt < 24; kt++) {
    const int cur = kt & 1;
    if (kt + 1 < 24) stageAB(kt + 1, cur ^ 1);
    const unsigned short* sA = sMem + cur * 4096;
    const unsigned short* sB = sMem + 8192 + cur * 4096;
    short8 af[4], bf[4];
#pragma unroll
    for (int i = 0; i < 4; i++)
      af[i] = *(const short8*)(sA + (wm * 64 + i * 16 + col15) * 32 + quad * 8);
#pragma unroll
    for (int j = 0; j < 4; j++)
      bf[j] = *(const short8*)(sB + (wn * 64 + j * 16 + col15) * 32 + quad * 8);
#pragma unroll
    for (int i = 0; i < 4; i++)
#pragma unroll
      for (int j = 0; j < 4; j++)
        acc[i][j] = __builtin_amdgcn_mfma_f32_16x16x32_bf16(af[i], bf[j], acc[i][j], 0, 0, 0);
    __syncthreads();
  }

  const int b = m0 >> 11;
  const int s0g = m0 & (Sn - 1);
  const int h0 = n0 >> 6;

  if (z < 2) {
    const float scl = (z == 0) ? QSCL : 1.0f;
    unsigned short* dst0 = (z == 0) ? Qc : Kc;
#pragma unroll
    for (int j = 0; j < 4; j++) {
      int nl = wn * 64 + j * 16 + col15;
      float bias_n = bias[n0 + nl];
#pragma unroll
      for (int i = 0; i < 4; i++) {
        int mb = wm * 64 + i * 16 + quad * 4;
#pragma unroll
        for (int r = 0; r < 4; r++) {
          int m = mb + r;
          sMem[m * 128 + (nl ^ (((m >> 2) & 3) << 4))] = f2bf((acc[i][j][r] + bias_n) * scl);
        }
      }
    }
    __syncthreads();
#pragma unroll
    for (int cc = 0; cc < 8; cc++) {
      int idx = cc * 256 + t;
      int m = idx >> 4, piece = idx & 15;
      int h = h0 + (piece >> 3), d8 = piece & 7;
      short8 v = *(const short8*)(sMem + m * 128 + (piece ^ (((m >> 2) & 3) << 1)) * 8);
      *(short8*)(dst0 + ((size_t)(b * Hn + h) * Sn + s0g + m) * 128 + d8 * 8) = v;
    }
  } else {
#pragma unroll
    for (int j = 0; j < 4; j++) {
      int nl = wn * 64 + j * 16 + col15;
      float bias_n = bias[n0 + nl];
#pragma unroll
      for (int i = 0; i < 4; i++) {
        int mb = wm * 64 + i * 16 + quad * 4;
        ushort4 pk = make_ushort4(f2bf(acc[i][j][0] + bias_n), f2bf(acc[i][j][1] + bias_n),
                                  f2bf(acc[i][j][2] + bias_n), f2bf(acc[i][j][3] + bias_n));
        *(ushort4*)(sMem + nl * 128 + (mb ^ ((nl & 7) << 4))) = pk;
      }
    }
    __syncthreads();
#pragma unroll
    for (int cc = 0; cc < 8; cc++) {
      int idx = cc * 256 + t;
      int nl = idx >> 4, piece = idx & 15;
      int h = h0 + (nl >> 6), d = nl & 63;
      short8 v = *(const short8*)(sMem + nl * 128 + (piece ^ ((nl & 7) << 1)) * 8);
      *(short8*)(Vt + ((size_t)(b * Hn + h) * 64 + d) * Sn + s0g + piece * 8) = v;
    }
  }
}

// ---------------- flash attention v4: v10 schedule, 8 waves x 16 q-rows ----------------
// S^T = mfma(K,Q): lane (quad,col15) reg r holds S[q = blk+col15][k = jm*16+quad*4+r].
// P trunc-packed -> 4x b64 sS writes/wave-tile (phys col = k ^ ((col15&7)<<3));
// PV reads b128 with same involution.  O^T = mfma(V^T, P^T).  lsum per-lane, quad-reduced.
// Schedule: QK(t) -> bar1 -> stage K(t+1)(single) + V(t+1)(dbuf) -> softmax+PV(t) -> bar2.
// LDS 48KB, 512 threads; launch_bounds arg2 = MIN BLOCKS/CU on this toolchain (r11
// evidence: (512,6) -> 40 VGPR + scratch spills). (512,3): 3 blocks/CU, 85-VGPR budget.
__global__ __launch_bounds__(512, 3)
void attn_kernel(const unsigned short* __restrict__ Qc,  // [BH][S][128], pre-scaled by QSCL
                 const unsigned short* __restrict__ Kc,  // [BH][S][128]
                 const unsigned short* __restrict__ Vt,  // [BH][64][S]
                 const float* __restrict__ mask,         // [B][S]
                 float* __restrict__ out) {              // [B][S][768]
  __shared__ __align__(16) unsigned short sK[64 * 128];     // 16KB single buffer, swizzled
  __shared__ __align__(16) unsigned short sV2[2][64 * 64];  // 16KB dbuf, swizzled
  __shared__ __align__(16) unsigned short sS[128 * 64];     // 16KB P^T, wave-private rows

  const int t = threadIdx.x;
  const int lane = t & 63, wave = t >> 6;                // wave 0..7
  const int quad = lane >> 4, col15 = lane & 15;
  const int swz = (col15 & 7) << 3;                      // sS k swizzle (shorts): phys = k ^ swz

  // XCD-aware swizzle: all 16 q-blocks of one bh share id&7 (L2 K/V reuse)
  const int id = blockIdx.x;
  const int slot = id >> 3;
  const int bh = (id & 7) + 8 * (slot >> 4);
  const int q0 = (slot & 15) * 128;
  const int b = bh / Hn, h = bh % Hn;

  // Q fragments (B-operand: col=q=lane&15, k-rows quad*8); 16 q-rows per wave
  short8 aq[4];
  const unsigned short* Qbase = Qc + ((size_t)bh * Sn + q0) * 128;
#pragma unroll
  for (int kk = 0; kk < 4; kk++)
    aq[kk] = *(const short8*)(Qbase + (size_t)(wave * 16 + col15) * 128 + kk * 32 + quad * 8);

  floatx4 O[4];
  float lsum = 0.f;
#pragma unroll
  for (int j = 0; j < 4; j++) O[j] = (floatx4){0.f, 0.f, 0.f, 0.f};

  const unsigned short* Kbase = Kc + (size_t)bh * Sn * 128;
  const unsigned short* Vbase = Vt + (size_t)bh * 64 * Sn;
  const float* mbase = mask + (size_t)b * Sn;

  const int krow = lane >> 4, kslot = lane & 15;  // sK staging: 4 rows/call
  const int vrow = lane >> 3, vslot = lane & 7;   // sV staging: 8 rows/call

  auto stageK = [&](int tile) {
#pragma unroll
    for (int c = 0; c < 2; c++) {                 // K tile 64x256B: 8 waves x 2 calls x 4 rows
      int row = wave * 8 + c * 4 + krow;
      int g = (kslot & 8) | ((kslot ^ row) & 7);
      async16(Kbase + (size_t)(tile * 64 + row) * 128 + g * 8, sK + (wave * 8 + c * 4) * 128);
    }
  };
  auto stageV = [&](int tile, int buf) {
    unsigned short* sVn = &sV2[buf][0];
    {                                             // V^T tile 64x128B: 8 waves x 1 call x 8 rows
      int row = wave * 8 + vrow;
      int g = vslot ^ (row & 7);
      async16(Vbase + (size_t)row * Sn + tile * 64 + g * 8, sVn + (wave * 8) * 64);
    }
  };

  constexpr int NT = Sn / 64;                     // 32 tiles
  stageK(0);
  stageV(0, 0);
  float mcur = mbase[lane] * LOG2E;               // tile-0 mask dword
  __syncthreads();                                // drain prologue staging

  for (int kt = 0; kt < NT; kt++) {
    const int cur = kt & 1;
    const unsigned short* sVcur = &sV2[cur][0];

    // ---- S^T(log2-domain) = Kcat Qcat^T  (reads sK) ----
    floatx4 sacc[4];                              // [jm = k subtile]
#pragma unroll
    for (int jm = 0; jm < 4; jm++) sacc[jm] = (floatx4){0.f, 0.f, 0.f, 0.f};
    __builtin_amdgcn_s_setprio(1);
#pragma unroll
    for (int kk = 0; kk < 4; kk++) {
      const int slotK = (((kk * 4 + quad) & 8) | (((kk * 4 + quad) ^ col15) & 7)) * 8;
#pragma unroll
      for (int jm = 0; jm < 4; jm++) {
        short8 ak = *(const short8*)(sK + (jm * 16 + col15) * 128 + slotK);
        sacc[jm] = __builtin_amdgcn_mfma_f32_16x16x32_bf16(ak, aq[kk], sacc[jm], 0, 0, 0);
      }
    }
    __builtin_amdgcn_s_setprio(0);

    const int tn = (kt + 1 < NT) ? kt + 1 : NT - 1;
    float mnew = mbase[tn * 64 + lane] * LOG2E;   // prefetch next tile's mask
    const bool nomask = __all(mcur == 0.0f);

    __syncthreads();                              // barrier1: all waves done reading sK
    if (kt + 1 < NT) {
      stageK(kt + 1);                             // rewrite single K buffer
      stageV(kt + 1, cur ^ 1);                    // fill other V buffer
    }

    // mask slow path: per-element additive value via lane shuffle (exact)
    float mvv[4][4];
    if (!nomask) {
#pragma unroll
      for (int jm = 0; jm < 4; jm++)
#pragma unroll
        for (int r = 0; r < 4; r++) mvv[jm][r] = __shfl(mcur, jm * 16 + quad * 4 + r);
    }

    // ---- softmax: p = exp2(s (+ mask)); trunc-pack -> b64 sS writes; lsum adds ----
    {
      unsigned short* srow = sS + (wave * 16 + col15) * 64;
      float lacc = 0.f;
#pragma unroll
      for (int jm = 0; jm < 4; jm++) {
        float p0 = sacc[jm][0], p1 = sacc[jm][1];
        float p2 = sacc[jm][2], p3 = sacc[jm][3];
        if (!nomask) { p0 += mvv[jm][0]; p1 += mvv[jm][1]; p2 += mvv[jm][2]; p3 += mvv[jm][3]; }
        unsigned u0 = __float_as_uint(__builtin_amdgcn_exp2f(p0)) & 0xFFFF0000u;
        unsigned u1 = __float_as_uint(__builtin_amdgcn_exp2f(p1)) & 0xFFFF0000u;
        unsigned u2 = __float_as_uint(__builtin_amdgcn_exp2f(p2)) & 0xFFFF0000u;
        unsigned u3 = __float_as_uint(__builtin_amdgcn_exp2f(p3)) & 0xFFFF0000u;
        lacc += (__uint_as_float(u0) + __uint_as_float(u1)) +
                (__uint_as_float(u2) + __uint_as_float(u3));
        uint2 w;
        w.x = (u0 >> 16) | u1;
        w.y = (u2 >> 16) | u3;
        *(uint2*)(srow + ((jm * 16 + quad * 4) ^ swz)) = w;
      }
      lsum += lacc;
    }
    // no barrier: sS rows are wave-private; intra-wave LDS RAW is ordered

    // ---- O^T += V^T P^T  (reads sS + sVcur) ----
    __builtin_amdgcn_s_setprio(1);
#pragma unroll
    for (int kk = 0; kk < 2; kk++) {
      short8 pb = *(const short8*)(sS + (wave * 16 + col15) * 64 + ((kk * 32 + quad * 8) ^ swz));
      const int slotV = ((kk * 4 + quad) ^ (col15 & 7)) * 8;
#pragma unroll
      for (int jd = 0; jd < 4; jd++) {
        short8 av = *(const short8*)(sVcur + (jd * 16 + col15) * 64 + slotV);
        O[jd] = __builtin_amdgcn_mfma_f32_16x16x32_bf16(av, pb, O[jd], 0, 0, 0);
      }
    }
    __builtin_amdgcn_s_setprio(0);

    __syncthreads();  // barrier2: drains K(t+1)/V(t+1) staging (issued ~900cy ago);
                      // all waves' PV reads of sVcur done before t+2 overwrites it
    mcur = mnew;
  }

  // ---- epilogue: l[q] = quad-reduced lsum; O^T cols divided, float4 stores ----
  {
    float s_ = lsum;
    s_ += __shfl_xor(s_, 16);
    s_ += __shfl_xor(s_, 32);
    float inv = 1.0f / s_;
    int qrow = q0 + wave * 16 + col15;
    float* obase = out + ((size_t)b * Sn + qrow) * Dn + h * 64 + quad * 4;
#pragma unroll
    for (int jd = 0; jd < 4; jd++) {
      float4 o4 = make_float4(O[jd][0] * inv, O[jd][1] * inv,
                              O[jd][2] * inv, O[jd][3] * inv);
      *(float4*)(obase + jd * 16) = o4;
    }
  }
}

extern "C" void kernel_launch(void* const* d_in, const int* in_sizes, int n_in,
                              void* d_out, int out_size, void* d_ws, size_t ws_size,
                              hipStream_t stream) {
  const float* hs   = (const float*)d_in[0];
  const float* lq   = (const float*)d_in[1];
  const float* lk   = (const float*)d_in[2];
  const float* mask = (const float*)d_in[3];
  const float* Wq   = (const float*)d_in[4];
  const float* bq   = (const float*)d_in[5];
  const float* Wk   = (const float*)d_in[6];
  const float* bk   = (const float*)d_in[7];
  const float* Wv   = (const float*)d_in[8];
  const float* bv   = (const float*)d_in[9];
  float* out = (float*)d_out;

  char* ws = (char*)d_ws;
  unsigned short* Xbf = (unsigned short*)ws;                         // [8192][768]
  unsigned short* Wbf = (unsigned short*)(ws + 12582912);            // [3][768][768]
  unsigned short* Qc  = (unsigned short*)(ws + 12582912 + 3538944);  // [48][2048][128]
  unsigned short* Kc  = Qc + (size_t)BHn * Sn * 128;
  unsigned short* Vt  = Kc + (size_t)BHn * Sn * 128;                 // [48][64][2048]

  cast_hs_kernel<<<6144, 256, 0, stream>>>(hs, Xbf, 1572864);
  cast_w_kernel<<<dim3(576, 3), 256, 0, stream>>>(Wq, Wk, Wv, Wbf);
  pack_layout_kernel<<<dim3(3072, 2), 256, 0, stream>>>(lq, lk, Qc, Kc);
  proj_kernel<<<dim3(6, 64, 3), 256, 0, stream>>>(Xbf, Wbf, bq, bk, bv, Qc, Kc, Vt);
  attn_kernel<<<768, 512, 0, stream>>>(Qc, Kc, Vt, mask, out);
}